// Round 16
// baseline (685.816 us; speedup 1.0000x reference)
//
#include <hip/hip_runtime.h>
#include <hip/hip_bf16.h>
#include <cstdint>
#include <cstddef>

// Problem constants (match reference)
static constexpr int B   = 4;
static constexpr int CIN = 256;
static constexpr int T   = 100;   // time / start dim
static constexpr int D   = 100;   // duration dim
static constexpr int S   = 32;    // num_sample bins
static constexpr int C1  = 128;   // reduced channels
static constexpr int DU  = D * T; // 10000

typedef __attribute__((ext_vector_type(8))) short bfv8;   // 8 bf16 (4 VGPR)
typedef __attribute__((ext_vector_type(4))) short bfv4;   // 4 bf16 (2 VGPR)
typedef __attribute__((ext_vector_type(4))) float fx4;    // MFMA accumulator
typedef unsigned short us;

static __device__ __forceinline__ unsigned short f2bf(float f) {
    unsigned int x = __float_as_uint(f);
    x += 0x7FFFu + ((x >> 16) & 1u);           // RNE to bf16
    return (unsigned short)(x >> 16);
}
static __device__ __forceinline__ unsigned int pk2(float a, float b) {
    return (unsigned int)f2bf(a) | ((unsigned int)f2bf(b) << 16);
}

#define MFMA16(A, Bq, C) __builtin_amdgcn_mfma_f32_16x16x32_bf16((A), (Bq), (C), 0, 0, 0)

// async global->LDS, 16B per lane; LDS dest = wave-uniform base + lane*16
static __device__ __forceinline__ void gload16(const void* g, void* l) {
    __builtin_amdgcn_global_load_lds(
        (const __attribute__((address_space(1))) void*)g,
        (__attribute__((address_space(3))) void*)l, 16, 0, 0);
}

// ---------------------------------------------------------------------------
// kPrep: fused weight transposes (one launch instead of four).
__global__ void kPrep(const float* __restrict__ w3d, us* __restrict__ w3B,
                      const float* __restrict__ w2d, us* __restrict__ w2b,
                      const float* __restrict__ wf1, us* __restrict__ wfb1,
                      const float* __restrict__ wf2, us* __restrict__ wfb2) {
    int bid = blockIdx.x;
    int t = threadIdx.x;
    if (bid < 8192) {
        int tid = bid * 256 + t;               // 2,097,152
        int c = tid & 127;
        int o = (tid >> 7) & 511;
        int s = tid >> 16;
        w3B[tid] = f2bf(w3d[(o * 128 + c) * 32 + s]);
    } else if (bid < 8448) {
        int tid = (bid - 8192) * 256 + t;      // 65,536
        w2b[tid] = f2bf(w2d[tid]);
    } else if (bid < 9024) {
        int tid = (bid - 8448) * 256 + t;      // 147,456
        int c   = tid & 127;
        int k   = (tid >> 7) & 127;
        int tap = tid >> 14;
        wfb1[tid] = f2bf(wf1[(size_t)(k * 128 + c) * 9 + tap]);
    } else {
        int tid = (bid - 9024) * 256 + t;      // 147,456
        int c   = tid & 127;
        int k   = (tid >> 7) & 127;
        int tap = tid >> 14;
        wfb2[tid] = f2bf(wf2[(size_t)(k * 128 + c) * 9 + tap]);
    }
}

// ---------------------------------------------------------------------------
// hT[b][t(128)][c] = bf16(relu(conv1d(x))), t>=100 zero-padded.
__global__ void kConv1d(const float* __restrict__ x, const float* __restrict__ wrd,
                        const float* __restrict__ brd, us* __restrict__ hT) {
    __shared__ float wl[CIN * 3];
    int b = blockIdx.x >> 7;
    int o = blockIdx.x & 127;
    for (int i = threadIdx.x; i < CIN * 3; i += blockDim.x)
        wl[i] = wrd[o * CIN * 3 + i];
    __syncthreads();
    int t = threadIdx.x;          // 0..127
    float val = 0.f;
    if (t < T) {
        float acc = brd[o];
        const float* xb = x + (size_t)b * CIN * T;
        for (int c = 0; c < CIN; ++c) {
            float xm = (t > 0)     ? xb[c * T + t - 1] : 0.f;
            float x0 =               xb[c * T + t];
            float xp = (t < T - 1) ? xb[c * T + t + 1] : 0.f;
            acc = fmaf(wl[c * 3 + 0], xm, acc);
            acc = fmaf(wl[c * 3 + 1], x0, acc);
            acc = fmaf(wl[c * 3 + 2], xp, acc);
        }
        val = fmaxf(acc, 0.f);
    }
    hT[((size_t)b * 128 + t) * 128 + o] = f2bf(val);
}

// ---------------------------------------------------------------------------
// QT[b][s][o][t(128)] = bf16(sum_c w3B[s][o][c] * hT[b][t][c])  -- MFMA GEMM
__global__ __launch_bounds__(256, 2)
void kQm(const us* __restrict__ w3B, const us* __restrict__ hT,
         us* __restrict__ QT) {
    int bid = blockIdx.x;            // 4*32*2 = 256
    int oh = bid & 1;
    int s  = (bid >> 1) & 31;
    int b  = bid >> 6;
    int tid = threadIdx.x;
    int w   = tid >> 6;
    int l   = tid & 63;
    int l15 = l & 15, lg = l >> 4;
    int obase = oh * 256 + w * 64;
    fx4 acc[4][8];
#pragma unroll
    for (int m = 0; m < 4; ++m)
#pragma unroll
        for (int n = 0; n < 8; ++n) acc[m][n] = (fx4){0.f, 0.f, 0.f, 0.f};

#pragma unroll
    for (int ks = 0; ks < 4; ++ks) {
        int kofs = ks * 32 + lg * 8;
        bfv8 a0 = *(const bfv8*)(w3B + (size_t)(s * 512 + obase + 0 * 16 + l15) * 128 + kofs);
        bfv8 a1 = *(const bfv8*)(w3B + (size_t)(s * 512 + obase + 1 * 16 + l15) * 128 + kofs);
        bfv8 a2 = *(const bfv8*)(w3B + (size_t)(s * 512 + obase + 2 * 16 + l15) * 128 + kofs);
        bfv8 a3 = *(const bfv8*)(w3B + (size_t)(s * 512 + obase + 3 * 16 + l15) * 128 + kofs);
#pragma unroll
        for (int n = 0; n < 8; ++n) {
            bfv8 bq = *(const bfv8*)(hT + (size_t)(b * 128 + n * 16 + l15) * 128 + kofs);
            acc[0][n] = MFMA16(a0, bq, acc[0][n]);
            acc[1][n] = MFMA16(a1, bq, acc[1][n]);
            acc[2][n] = MFMA16(a2, bq, acc[2][n]);
            acc[3][n] = MFMA16(a3, bq, acc[3][n]);
        }
    }
    us* outb = QT + (size_t)(b * 32 + s) * 512 * 128;
#pragma unroll
    for (int m = 0; m < 4; ++m)
#pragma unroll
        for (int n = 0; n < 8; ++n)
#pragma unroll
            for (int r = 0; r < 4; ++r) {
                int o = obase + m * 16 + lg * 4 + r;
                outb[(size_t)o * 128 + n * 16 + l15] = f2bf(acc[m][n][r]);
            }
}

// ---------------------------------------------------------------------------
// maskW pre-pass: gather bf16 A-fragments once, d-QUAD layout.
// slot (s, dq, ut): 4 dd x 64 lanes x 16B = 2048 us; shared t0 per quad
// (width proof: quad span <= 23.56 -> fits K=32 with 4-us-aligned t0).
__global__ __launch_bounds__(256, 4)
void kMaskW(const float* __restrict__ mask, us* __restrict__ maskW) {
    int bid = blockIdx.x;            // (s*25+dq)*7+ut = 5600
    int ut = bid % 7;
    int dq = (bid / 7) % 25;
    int s  = bid / 175;
    int tid = threadIdx.x;           // 256: dd*64 + l
    int dd = tid >> 6;
    int l  = tid & 63;
    int l15 = l & 15, lg = l >> 4;
    int u0 = ut * 16;
    int d0 = dq * 4;

    float fs1 = (float)(3 * s), fs2 = (float)(3 * s + 2);
    float pmin = 1e30f, pmax = -1e30f;
#pragma unroll
    for (int j = 0; j < 4; ++j) {
        float dj = (float)(d0 + j);
        float step = (2.f * dj + 1.f) * (1.f / 95.f);
        float xoff = -0.5f * (dj + 1.f);
        pmin = fminf(pmin, xoff + fs1 * step);
        pmax = fmaxf(pmax, xoff + fs2 * step);
    }
    float pminT = (float)u0 + pmin;
    float pmaxT = (float)(u0 + 15) + pmax;
    bool skip = (pminT > 100.01f) || (pmaxT < -1.01f);
    int t0 = (int)floorf(pminT) - 1;
    if (t0 < 0) t0 = 0;
    t0 &= ~3;
    if (t0 > 96) t0 = 96;

    int u = u0 + l15;
    int d = d0 + dd;
    float v[8];
#pragma unroll
    for (int j = 0; j < 8; ++j) {
        int t = t0 + lg * 8 + j;
        v[j] = 0.f;
        if (!skip && t < 100 && u < 100)
            v[j] = mask[(((size_t)t * 32 + s) * 100 + d) * 100 + u];
    }
    uint4 pk;
    pk.x = pk2(v[0], v[1]); pk.y = pk2(v[2], v[3]);
    pk.z = pk2(v[4], v[5]); pk.w = pk2(v[6], v[7]);
    *(uint4*)(maskW + (size_t)bid * 2048 + tid * 8) = pk;
}

// ---------------------------------------------------------------------------
// m3b: MFMA, compacted s-list, XCD L2-pinned, d-QUAD fused. 12 batched loads
// per 16 MFMAs. launch_bounds(128,8): VGPR<=64 -> up to 16 blocks/CU of TLP.
__global__ __launch_bounds__(128, 8)
void kM3m(const us* __restrict__ maskW, const us* __restrict__ QT,
          const float* __restrict__ b3d, us* __restrict__ m3b) {
    __shared__ int sl[32];
    __shared__ int nsh;
    int bid = blockIdx.x;            // 2800
    int x  = bid & 7;                // XCD id (round-robin dispatch)
    int b  = x >> 1;
    int ohalf = x & 1;
    int i  = bid >> 3;               // 0..349
    int dq = i / 14;
    int r2 = i % 14;
    int ut = r2 >> 1;
    int os = r2 & 1;
    int u0 = ut * 16;
    int d0 = dq * 4;
    int tid = threadIdx.x;           // 128
    int w   = tid >> 6;              // 0..1
    int l   = tid & 63;
    int l15 = l & 15, lg = l >> 4;
    int obase = ohalf * 256 + os * 128 + w * 64;

    // first wave builds compacted (s, t0) list -- MUST match kMaskW's formula
    if (tid < 64) {
        int s = tid;
        float fs1 = (float)(3 * s), fs2 = (float)(3 * s + 2);
        float pmin = 1e30f, pmax = -1e30f;
#pragma unroll
        for (int j = 0; j < 4; ++j) {
            float dj = (float)(d0 + j);
            float step = (2.f * dj + 1.f) * (1.f / 95.f);
            float xoff = -0.5f * (dj + 1.f);
            pmin = fminf(pmin, xoff + fs1 * step);
            pmax = fmaxf(pmax, xoff + fs2 * step);
        }
        float pminT = (float)u0 + pmin;
        float pmaxT = (float)(u0 + 15) + pmax;
        bool valid = (s < 32) && !((pminT > 100.01f) || (pmaxT < -1.01f));
        int t0 = (int)floorf(pminT) - 1;
        if (t0 < 0) t0 = 0;
        t0 &= ~3;
        if (t0 > 96) t0 = 96;
        unsigned long long mb = __ballot(valid);
        int rank = __popcll(mb & ((1ull << tid) - 1ull));
        if (valid) sl[rank] = (t0 << 8) | s;
        if (tid == 0) nsh = (int)__popcll(mb);
    }
    __syncthreads();
    int ns = nsh;

    fx4 acc[4][4];
#pragma unroll
    for (int m = 0; m < 4; ++m)
#pragma unroll
        for (int n = 0; n < 4; ++n) acc[m][n] = (fx4){0.f, 0.f, 0.f, 0.f};

    const us* QTb = QT + (size_t)b * 32 * 65536
                       + (size_t)(obase + l15) * 128 + lg * 8;
    const us* mwBase = maskW + (size_t)(dq * 7 + ut) * 2048 + l * 8;

    for (int si = 0; si < ns; ++si) {
        int pk = sl[si];
        int s_ = pk & 255, t0_ = pk >> 8;
        const us* mw = mwBase + (size_t)s_ * 358400;
        bfv8 A0 = *(const bfv8*)(mw);
        bfv8 A1 = *(const bfv8*)(mw + 512);
        bfv8 A2 = *(const bfv8*)(mw + 1024);
        bfv8 A3 = *(const bfv8*)(mw + 1536);
        const us* qs = QTb + (size_t)s_ * 65536 + t0_;
        bfv4 b0l = *(const bfv4*)(qs);        bfv4 b0h = *(const bfv4*)(qs + 4);
        bfv4 b1l = *(const bfv4*)(qs + 2048); bfv4 b1h = *(const bfv4*)(qs + 2052);
        bfv4 b2l = *(const bfv4*)(qs + 4096); bfv4 b2h = *(const bfv4*)(qs + 4100);
        bfv4 b3l = *(const bfv4*)(qs + 6144); bfv4 b3h = *(const bfv4*)(qs + 6148);
        bfv8 B0 = __builtin_shufflevector(b0l, b0h, 0, 1, 2, 3, 4, 5, 6, 7);
        bfv8 B1 = __builtin_shufflevector(b1l, b1h, 0, 1, 2, 3, 4, 5, 6, 7);
        bfv8 B2 = __builtin_shufflevector(b2l, b2h, 0, 1, 2, 3, 4, 5, 6, 7);
        bfv8 B3 = __builtin_shufflevector(b3l, b3h, 0, 1, 2, 3, 4, 5, 6, 7);
        __builtin_amdgcn_s_setprio(1);
        acc[0][0] = MFMA16(A0, B0, acc[0][0]);  acc[1][0] = MFMA16(A1, B0, acc[1][0]);
        acc[2][0] = MFMA16(A2, B0, acc[2][0]);  acc[3][0] = MFMA16(A3, B0, acc[3][0]);
        acc[0][1] = MFMA16(A0, B1, acc[0][1]);  acc[1][1] = MFMA16(A1, B1, acc[1][1]);
        acc[2][1] = MFMA16(A2, B1, acc[2][1]);  acc[3][1] = MFMA16(A3, B1, acc[3][1]);
        acc[0][2] = MFMA16(A0, B2, acc[0][2]);  acc[1][2] = MFMA16(A1, B2, acc[1][2]);
        acc[2][2] = MFMA16(A2, B2, acc[2][2]);  acc[3][2] = MFMA16(A3, B2, acc[3][2]);
        acc[0][3] = MFMA16(A0, B3, acc[0][3]);  acc[1][3] = MFMA16(A1, B3, acc[1][3]);
        acc[2][3] = MFMA16(A2, B3, acc[2][3]);  acc[3][3] = MFMA16(A3, B3, acc[3][3]);
        __builtin_amdgcn_s_setprio(0);
    }

#pragma unroll
    for (int dd = 0; dd < 4; ++dd) {
#pragma unroll
        for (int n = 0; n < 4; ++n) {
            int o = obase + n * 16 + l15;
            float bias = b3d[o];
#pragma unroll
            for (int r4 = 0; r4 < 4; ++r4) {
                int u = u0 + lg * 4 + r4;
                if (u < 100)
                    m3b[((size_t)b * DU + (d0 + dd) * 100 + u) * 512 + o] =
                        f2bf(fmaxf(acc[dd][n][r4] + bias, 0.f));
            }
        }
    }
}

// ---------------------------------------------------------------------------
// m2b[b][du][k] = bf16(relu(b2d[k] + sum_o m3b*w2b))  -- MFMA GEMM
__global__ __launch_bounds__(256, 4)
void kM2m(const us* __restrict__ m3b, const us* __restrict__ w2b,
          const float* __restrict__ b2d, us* __restrict__ m2b) {
    int blk  = blockIdx.x;           // 4 * 157
    int tile = blk % 157;
    int b    = blk / 157;
    int du0  = tile * 64;
    int tid = threadIdx.x;
    int w   = tid >> 6;              // wave -> du sub-tile of 16
    int l   = tid & 63;
    int l15 = l & 15, lg = l >> 4;
    fx4 acc[8];
#pragma unroll
    for (int n = 0; n < 8; ++n) acc[n] = (fx4){0.f, 0.f, 0.f, 0.f};

    int dua = du0 + w * 16 + l15; if (dua > 9999) dua = 9999;   // ragged clamp
    const us* ap = m3b + ((size_t)b * DU + dua) * 512;
#pragma unroll 4
    for (int ks = 0; ks < 16; ++ks) {
        bfv8 a = *(const bfv8*)(ap + ks * 32 + lg * 8);
#pragma unroll
        for (int n = 0; n < 8; ++n) {
            bfv8 bq = *(const bfv8*)(w2b + (size_t)(n * 16 + l15) * 512 + ks * 32 + lg * 8);
            acc[n] = MFMA16(a, bq, acc[n]);
        }
    }
#pragma unroll
    for (int n = 0; n < 8; ++n) {
        int k = n * 16 + l15;
        float bias = b2d[k];
#pragma unroll
        for (int r = 0; r < 4; ++r) {
            int du = du0 + w * 16 + lg * 4 + r;
            if (du < DU)
                m2b[((size_t)b * DU + du) * 128 + k] = f2bf(fmaxf(acc[n][r] + bias, 0.f));
        }
    }
}

// ---------------------------------------------------------------------------
// 3x3 conv 128->128 (bf16 in), implicit GEMM, T3 2-phase W pipeline.
// HEAD=0: write bf16 fout.  HEAD=1: fuse 2-ch head + sigmoid, write hout.
template<int HEAD>
__global__ __launch_bounds__(256, 2)
void kConvM(const us* __restrict__ fin, const us* __restrict__ wfb,
            const float* __restrict__ bf, us* __restrict__ fout,
            const float* __restrict__ wf3, const float* __restrict__ bf3,
            float* __restrict__ hout) {
    __shared__ us slab[6 * 18 * 128];   // 27.6 KB, XOR-swizzled rows (256B pitch)
    __shared__ us wl2[2][8192];         // 2 x 16 KB: [k(128)][c-half(64)], 128B pitch
    int blk = blockIdx.x;            // b*175 + dt*7 + ut = 700
    int ut = blk % 7;
    int dt = (blk / 7) % 25;
    int b  = blk / 175;
    int u0 = ut * 16, d0 = dt * 4;
    int tid = threadIdx.x;
    int w   = tid >> 6;
    int l   = tid & 63;
    int l15 = l & 15, lg = l >> 4;
    fx4 acc[8];
#pragma unroll
    for (int n = 0; n < 8; ++n) acc[n] = (fx4){0.f, 0.f, 0.f, 0.f};

#define STAGE_W(BUF, P)                                                        \
    {   const int tap_ = (P) >> 1, ch_ = (P) & 1;                              \
        const us* wsrc = wfb + (size_t)tap_ * 16384 + ch_ * 64;                \
        _Pragma("unroll")                                                      \
        for (int rr = 0; rr < 4; ++rr) {                                       \
            int seg = rr * 4 + w;                                              \
            int off = seg * 1024 + l * 16;                                     \
            int k_ = off >> 7, cb_ = off & 127;                                \
            int cbs = cb_ ^ ((k_ & 7) << 4);                                   \
            gload16(wsrc + (size_t)k_ * 128 + (cbs >> 1),                      \
                    (char*)&wl2[BUF][0] + seg * 1024);                         \
        }                                                                      \
    }

    // stage input slab (bf16): rows (dd,uu) = fin[b][d0-1+dd][u0-1+uu][c]
    for (int i = tid; i < 1728; i += 256) {         // 16B chunks (8 c each)
        int cc = i & 15;
        int uu = (i >> 4) % 18;
        int dd = (i >> 4) / 18;
        int dr = d0 - 1 + dd, su = u0 - 1 + uu;
        uint4 v = {0u, 0u, 0u, 0u};
        if (dr >= 0 && dr < 100 && su >= 0 && su < 100)
            v = *(const uint4*)(fin + ((size_t)b * DU + dr * 100 + su) * 128 + cc * 8);
        int byte = (dd * 18 + uu) * 256 + ((cc * 16) ^ ((uu & 7) << 4));
        *(uint4*)((char*)slab + byte) = v;
    }
    STAGE_W(0, 0)
    __syncthreads();                                 // slab + W(0) ready

#pragma unroll
    for (int p = 0; p < 18; ++p) {
        if (p + 1 < 18) STAGE_W((p + 1) & 1, p + 1)  // prefetch next W tile
        const int tap = p >> 1, ch = p & 1;
        const int dy = tap / 3, dx = tap % 3;
        int uu = l15 + dx;
        int ddr = w + dy;
        int arow = (ddr * 18 + uu) * 256;
        int aswz = (uu & 7) << 4;
        const char* wbuf = (const char*)&wl2[p & 1][0];
#pragma unroll
        for (int cs = 0; cs < 2; ++cs) {
            int cbyte = ch * 128 + cs * 64 + lg * 16;    // slab byte within row
            bfv8 a = *(const bfv8*)((const char*)slab + arow + (cbyte ^ aswz));
            int wcb = cs * 64 + lg * 16;                 // W byte within row
#pragma unroll
            for (int n = 0; n < 8; ++n) {
                int k = n * 16 + l15;
                bfv8 bq = *(const bfv8*)(wbuf + k * 128 + (wcb ^ ((k & 7) << 4)));
                acc[n] = MFMA16(a, bq, acc[n]);
            }
        }
        __syncthreads();    // drains gload vmcnt: next buffer ready; reads done
    }
#undef STAGE_W

    int d = d0 + w;
    if (HEAD == 0) {
#pragma unroll
        for (int n = 0; n < 8; ++n) {
            int k = n * 16 + l15;
            float bias = bf[k];
#pragma unroll
            for (int r = 0; r < 4; ++r) {
                int u = u0 + lg * 4 + r;
                if (u < 100)
                    fout[((size_t)b * DU + d * 100 + u) * 128 + k] =
                        f2bf(fmaxf(acc[n][r] + bias, 0.f));
            }
        }
    } else {
#pragma unroll
        for (int r = 0; r < 4; ++r) {
            float p0 = 0.f, p1 = 0.f;
#pragma unroll
            for (int n = 0; n < 8; ++n) {
                int k = n * 16 + l15;
                float f = fmaxf(acc[n][r] + bf[k], 0.f);
                p0 = fmaf(f, wf3[k], p0);
                p1 = fmaf(f, wf3[128 + k], p1);
            }
            p0 += __shfl_xor(p0, 1); p0 += __shfl_xor(p0, 2);
            p0 += __shfl_xor(p0, 4); p0 += __shfl_xor(p0, 8);
            p1 += __shfl_xor(p1, 1); p1 += __shfl_xor(p1, 2);
            p1 += __shfl_xor(p1, 4); p1 += __shfl_xor(p1, 8);
            int u = u0 + lg * 4 + r;
            if (l15 == 0 && u < 100) {
                int du = d * 100 + u;
                hout[((size_t)b * 2 + 0) * DU + du] = 1.f / (1.f + expf(-(p0 + bf3[0])));
                hout[((size_t)b * 2 + 1) * DU + du] = 1.f / (1.f + expf(-(p1 + bf3[1])));
            }
        }
    }
}

// ---------------------------------------------------------------------------
extern "C" void kernel_launch(void* const* d_in, const int* in_sizes, int n_in,
                              void* d_out, int out_size, void* d_ws, size_t ws_size,
                              hipStream_t stream) {
    const float* x    = (const float*)d_in[0];
    const float* wrd  = (const float*)d_in[1];
    const float* brd  = (const float*)d_in[2];
    const float* w3d  = (const float*)d_in[3];
    const float* b3d  = (const float*)d_in[4];
    const float* w2d  = (const float*)d_in[5];
    const float* b2d  = (const float*)d_in[6];
    const float* wf1  = (const float*)d_in[7];
    const float* bf1  = (const float*)d_in[8];
    const float* wf2  = (const float*)d_in[9];
    const float* bf2  = (const float*)d_in[10];
    const float* wf3  = (const float*)d_in[11];
    const float* bf3  = (const float*)d_in[12];
    const float* mask = (const float*)d_in[13];

    float* ws = (float*)d_ws;
    // layout (float-unit offsets)
    us* hT    = (us*)(ws + 0);            //    65,536 us -> [0, 32768)
    us* w3B   = (us*)(ws + 32768);        // 2,097,152 us -> [32768, 1081344)
    us* w2b   = (us*)(ws + 1081344);      //    65,536 us -> [.., 1114112)
    us* wfb1  = (us*)(ws + 1114112);      //   147,456 us -> [.., 1187840)
    us* wfb2  = (us*)(ws + 1187840);      //   147,456 us -> [.., 1261568)
    us* QT    = (us*)(ws + 1261568);      // 8,388,608 us -> [.., 5455872)
    us* maskW = (us*)(ws + 5455872);      // 11,468,800 us -> [.., 11190272)
    us* m2b   = (us*)(ws + 5455872);      // alias maskW (dead after kM3m)
    us* f1b   = (us*)(ws + 8015872);      // alias maskW tail
    us* m3b   = (us*)(ws + 11190272);     // 20,480,000 us -> [.., 21430272)

    kPrep<<<9600, 256, 0, stream>>>(w3d, w3B, w2d, w2b, wf1, wfb1, wf2, wfb2);
    kConv1d<<<B * C1, 128, 0, stream>>>(x, wrd, brd, hT);
    kMaskW<<<5600, 256, 0, stream>>>(mask, maskW);
    kQm<<<256, 256, 0, stream>>>(w3B, hT, QT);
    kM3m<<<2800, 128, 0, stream>>>(maskW, QT, b3d, m3b);
    kM2m<<<B * 157, 256, 0, stream>>>(m3b, w2b, b2d, m2b);
    kConvM<0><<<B * 25 * 7, 256, 0, stream>>>(m2b, wfb1, bf1, f1b,
                                              nullptr, nullptr, nullptr);
    kConvM<1><<<B * 25 * 7, 256, 0, stream>>>(f1b, wfb2, bf2, nullptr,
                                              wf3, bf3, (float*)d_out);
}

// Round 17
// 281.899 us; speedup vs baseline: 2.4328x; 2.4328x over previous
//
#include <hip/hip_runtime.h>
#include <hip/hip_bf16.h>
#include <cstdint>
#include <cstddef>

// Problem constants (match reference)
static constexpr int B   = 4;
static constexpr int CIN = 256;
static constexpr int T   = 100;   // time / start dim
static constexpr int D   = 100;   // duration dim
static constexpr int S   = 32;    // num_sample bins
static constexpr int C1  = 128;   // reduced channels
static constexpr int DU  = D * T; // 10000

typedef __attribute__((ext_vector_type(8))) short bfv8;   // 8 bf16 (4 VGPR)
typedef __attribute__((ext_vector_type(4))) short bfv4;   // 4 bf16 (2 VGPR)
typedef __attribute__((ext_vector_type(4))) float fx4;    // MFMA accumulator
typedef unsigned short us;

static __device__ __forceinline__ unsigned short f2bf(float f) {
    unsigned int x = __float_as_uint(f);
    x += 0x7FFFu + ((x >> 16) & 1u);           // RNE to bf16
    return (unsigned short)(x >> 16);
}
static __device__ __forceinline__ unsigned int pk2(float a, float b) {
    return (unsigned int)f2bf(a) | ((unsigned int)f2bf(b) << 16);
}

#define MFMA16(A, Bq, C) __builtin_amdgcn_mfma_f32_16x16x32_bf16((A), (Bq), (C), 0, 0, 0)

// async global->LDS, 16B per lane; LDS dest = wave-uniform base + lane*16
static __device__ __forceinline__ void gload16(const void* g, void* l) {
    __builtin_amdgcn_global_load_lds(
        (const __attribute__((address_space(1))) void*)g,
        (__attribute__((address_space(3))) void*)l, 16, 0, 0);
}

// ---------------------------------------------------------------------------
// kFront: fused independent front-end work (one launch, three sections):
//   [0,9600)      weight transposes (kPrep)
//   [9600,9856)   conv1d -> hT      (2 output channels per 256-thr block)
//   [9856,15456)  maskW d-quad gather
__global__ __launch_bounds__(256)
void kFront(const float* __restrict__ w3d, us* __restrict__ w3B,
            const float* __restrict__ w2d, us* __restrict__ w2b,
            const float* __restrict__ wf1, us* __restrict__ wfb1,
            const float* __restrict__ wf2, us* __restrict__ wfb2,
            const float* __restrict__ x,  const float* __restrict__ wrd,
            const float* __restrict__ brd, us* __restrict__ hT,
            const float* __restrict__ mask, us* __restrict__ maskW) {
    __shared__ float wl[2][CIN * 3];
    int bid = blockIdx.x;
    int t = threadIdx.x;
    if (bid < 8192) {
        int tid = bid * 256 + t;               // 2,097,152
        int c = tid & 127;
        int o = (tid >> 7) & 511;
        int s = tid >> 16;
        w3B[tid] = f2bf(w3d[(o * 128 + c) * 32 + s]);
        return;
    }
    if (bid < 8448) {
        int tid = (bid - 8192) * 256 + t;      // 65,536
        w2b[tid] = f2bf(w2d[tid]);
        return;
    }
    if (bid < 9024) {
        int tid = (bid - 8448) * 256 + t;      // 147,456
        int c   = tid & 127;
        int k   = (tid >> 7) & 127;
        int tap = tid >> 14;
        wfb1[tid] = f2bf(wf1[(size_t)(k * 128 + c) * 9 + tap]);
        return;
    }
    if (bid < 9600) {
        int tid = (bid - 9024) * 256 + t;      // 147,456
        int c   = tid & 127;
        int k   = (tid >> 7) & 127;
        int tap = tid >> 14;
        wfb2[tid] = f2bf(wf2[(size_t)(k * 128 + c) * 9 + tap]);
        return;
    }
    if (bid < 9856) {
        // conv1d: block j handles (b, o0) and (b, o0+1)
        int j = bid - 9600;                    // 0..255
        int b  = j >> 6;
        int op = j & 63;
        int half = t >> 7;
        int lt   = t & 127;
        int o = op * 2 + half;
        for (int i = lt; i < CIN * 3; i += 128)
            wl[half][i] = wrd[o * CIN * 3 + i];
        __syncthreads();
        int tt = lt;                           // 0..127
        float val = 0.f;
        if (tt < T) {
            float acc = brd[o];
            const float* xb = x + (size_t)b * CIN * T;
            for (int c = 0; c < CIN; ++c) {
                float xm = (tt > 0)     ? xb[c * T + tt - 1] : 0.f;
                float x0 =                xb[c * T + tt];
                float xp = (tt < T - 1) ? xb[c * T + tt + 1] : 0.f;
                acc = fmaf(wl[half][c * 3 + 0], xm, acc);
                acc = fmaf(wl[half][c * 3 + 1], x0, acc);
                acc = fmaf(wl[half][c * 3 + 2], xp, acc);
            }
            val = fmaxf(acc, 0.f);
        }
        hT[((size_t)b * 128 + tt) * 128 + o] = f2bf(val);
        return;
    }
    {
        // maskW gather: d-QUAD layout; slot (s,dq,ut): 4dd x 64 lanes x 16B
        int mb = bid - 9856;                   // 0..5599 = (s*25+dq)*7+ut
        int ut = mb % 7;
        int dq = (mb / 7) % 25;
        int s  = mb / 175;
        int dd = t >> 6;
        int l  = t & 63;
        int l15 = l & 15, lg = l >> 4;
        int u0 = ut * 16;
        int d0 = dq * 4;

        float fs1 = (float)(3 * s), fs2 = (float)(3 * s + 2);
        float pmin = 1e30f, pmax = -1e30f;
#pragma unroll
        for (int j = 0; j < 4; ++j) {
            float dj = (float)(d0 + j);
            float step = (2.f * dj + 1.f) * (1.f / 95.f);
            float xoff = -0.5f * (dj + 1.f);
            pmin = fminf(pmin, xoff + fs1 * step);
            pmax = fmaxf(pmax, xoff + fs2 * step);
        }
        float pminT = (float)u0 + pmin;
        float pmaxT = (float)(u0 + 15) + pmax;
        bool skip = (pminT > 100.01f) || (pmaxT < -1.01f);
        int t0 = (int)floorf(pminT) - 1;
        if (t0 < 0) t0 = 0;
        t0 &= ~3;
        if (t0 > 96) t0 = 96;

        int u = u0 + l15;
        int d = d0 + dd;
        float v[8];
#pragma unroll
        for (int j = 0; j < 8; ++j) {
            int tt = t0 + lg * 8 + j;
            v[j] = 0.f;
            if (!skip && tt < 100 && u < 100)
                v[j] = mask[(((size_t)tt * 32 + s) * 100 + d) * 100 + u];
        }
        uint4 pk;
        pk.x = pk2(v[0], v[1]); pk.y = pk2(v[2], v[3]);
        pk.z = pk2(v[4], v[5]); pk.w = pk2(v[6], v[7]);
        *(uint4*)(maskW + (size_t)mb * 2048 + t * 8) = pk;
    }
}

// ---------------------------------------------------------------------------
// QT[b][s][o][t(128)] = bf16(sum_c w3B[s][o][c] * hT[b][t][c])  -- MFMA GEMM
__global__ __launch_bounds__(256, 2)
void kQm(const us* __restrict__ w3B, const us* __restrict__ hT,
         us* __restrict__ QT) {
    int bid = blockIdx.x;            // 4*32*2 = 256
    int oh = bid & 1;
    int s  = (bid >> 1) & 31;
    int b  = bid >> 6;
    int tid = threadIdx.x;
    int w   = tid >> 6;
    int l   = tid & 63;
    int l15 = l & 15, lg = l >> 4;
    int obase = oh * 256 + w * 64;
    fx4 acc[4][8];
#pragma unroll
    for (int m = 0; m < 4; ++m)
#pragma unroll
        for (int n = 0; n < 8; ++n) acc[m][n] = (fx4){0.f, 0.f, 0.f, 0.f};

#pragma unroll
    for (int ks = 0; ks < 4; ++ks) {
        int kofs = ks * 32 + lg * 8;
        bfv8 a0 = *(const bfv8*)(w3B + (size_t)(s * 512 + obase + 0 * 16 + l15) * 128 + kofs);
        bfv8 a1 = *(const bfv8*)(w3B + (size_t)(s * 512 + obase + 1 * 16 + l15) * 128 + kofs);
        bfv8 a2 = *(const bfv8*)(w3B + (size_t)(s * 512 + obase + 2 * 16 + l15) * 128 + kofs);
        bfv8 a3 = *(const bfv8*)(w3B + (size_t)(s * 512 + obase + 3 * 16 + l15) * 128 + kofs);
#pragma unroll
        for (int n = 0; n < 8; ++n) {
            bfv8 bq = *(const bfv8*)(hT + (size_t)(b * 128 + n * 16 + l15) * 128 + kofs);
            acc[0][n] = MFMA16(a0, bq, acc[0][n]);
            acc[1][n] = MFMA16(a1, bq, acc[1][n]);
            acc[2][n] = MFMA16(a2, bq, acc[2][n]);
            acc[3][n] = MFMA16(a3, bq, acc[3][n]);
        }
    }
    us* outb = QT + (size_t)(b * 32 + s) * 512 * 128;
#pragma unroll
    for (int m = 0; m < 4; ++m)
#pragma unroll
        for (int n = 0; n < 8; ++n)
#pragma unroll
            for (int r = 0; r < 4; ++r) {
                int o = obase + m * 16 + lg * 4 + r;
                outb[(size_t)o * 128 + n * 16 + l15] = f2bf(acc[m][n][r]);
            }
}

// ---------------------------------------------------------------------------
// m3b: MFMA, compacted s-list, XCD L2-pinned, d-QUAD fused. 12 batched loads
// per 16 MFMAs. launch_bounds(128,4): 64 AGPR acc + working set needs the
// 128-VGPR/wave budget -- (128,8) spills catastrophically (r16 post-mortem).
__global__ __launch_bounds__(128, 4)
void kM3m(const us* __restrict__ maskW, const us* __restrict__ QT,
          const float* __restrict__ b3d, us* __restrict__ m3b) {
    __shared__ int sl[32];
    __shared__ int nsh;
    int bid = blockIdx.x;            // 2800
    int x  = bid & 7;                // XCD id (round-robin dispatch)
    int b  = x >> 1;
    int ohalf = x & 1;
    int i  = bid >> 3;               // 0..349
    int dq = i / 14;
    int r2 = i % 14;
    int ut = r2 >> 1;
    int os = r2 & 1;
    int u0 = ut * 16;
    int d0 = dq * 4;
    int tid = threadIdx.x;           // 128
    int w   = tid >> 6;              // 0..1
    int l   = tid & 63;
    int l15 = l & 15, lg = l >> 4;
    int obase = ohalf * 256 + os * 128 + w * 64;

    // first wave builds compacted (s, t0) list -- MUST match kFront's formula
    if (tid < 64) {
        int s = tid;
        float fs1 = (float)(3 * s), fs2 = (float)(3 * s + 2);
        float pmin = 1e30f, pmax = -1e30f;
#pragma unroll
        for (int j = 0; j < 4; ++j) {
            float dj = (float)(d0 + j);
            float step = (2.f * dj + 1.f) * (1.f / 95.f);
            float xoff = -0.5f * (dj + 1.f);
            pmin = fminf(pmin, xoff + fs1 * step);
            pmax = fmaxf(pmax, xoff + fs2 * step);
        }
        float pminT = (float)u0 + pmin;
        float pmaxT = (float)(u0 + 15) + pmax;
        bool valid = (s < 32) && !((pminT > 100.01f) || (pmaxT < -1.01f));
        int t0 = (int)floorf(pminT) - 1;
        if (t0 < 0) t0 = 0;
        t0 &= ~3;
        if (t0 > 96) t0 = 96;
        unsigned long long mb = __ballot(valid);
        int rank = __popcll(mb & ((1ull << tid) - 1ull));
        if (valid) sl[rank] = (t0 << 8) | s;
        if (tid == 0) nsh = (int)__popcll(mb);
    }
    __syncthreads();
    int ns = nsh;

    fx4 acc[4][4];
#pragma unroll
    for (int m = 0; m < 4; ++m)
#pragma unroll
        for (int n = 0; n < 4; ++n) acc[m][n] = (fx4){0.f, 0.f, 0.f, 0.f};

    const us* QTb = QT + (size_t)b * 32 * 65536
                       + (size_t)(obase + l15) * 128 + lg * 8;
    const us* mwBase = maskW + (size_t)(dq * 7 + ut) * 2048 + l * 8;

    for (int si = 0; si < ns; ++si) {
        int pk = sl[si];
        int s_ = pk & 255, t0_ = pk >> 8;
        const us* mw = mwBase + (size_t)s_ * 358400;
        bfv8 A0 = *(const bfv8*)(mw);
        bfv8 A1 = *(const bfv8*)(mw + 512);
        bfv8 A2 = *(const bfv8*)(mw + 1024);
        bfv8 A3 = *(const bfv8*)(mw + 1536);
        const us* qs = QTb + (size_t)s_ * 65536 + t0_;
        bfv4 b0l = *(const bfv4*)(qs);        bfv4 b0h = *(const bfv4*)(qs + 4);
        bfv4 b1l = *(const bfv4*)(qs + 2048); bfv4 b1h = *(const bfv4*)(qs + 2052);
        bfv4 b2l = *(const bfv4*)(qs + 4096); bfv4 b2h = *(const bfv4*)(qs + 4100);
        bfv4 b3l = *(const bfv4*)(qs + 6144); bfv4 b3h = *(const bfv4*)(qs + 6148);
        bfv8 B0 = __builtin_shufflevector(b0l, b0h, 0, 1, 2, 3, 4, 5, 6, 7);
        bfv8 B1 = __builtin_shufflevector(b1l, b1h, 0, 1, 2, 3, 4, 5, 6, 7);
        bfv8 B2 = __builtin_shufflevector(b2l, b2h, 0, 1, 2, 3, 4, 5, 6, 7);
        bfv8 B3 = __builtin_shufflevector(b3l, b3h, 0, 1, 2, 3, 4, 5, 6, 7);
        __builtin_amdgcn_s_setprio(1);
        acc[0][0] = MFMA16(A0, B0, acc[0][0]);  acc[1][0] = MFMA16(A1, B0, acc[1][0]);
        acc[2][0] = MFMA16(A2, B0, acc[2][0]);  acc[3][0] = MFMA16(A3, B0, acc[3][0]);
        acc[0][1] = MFMA16(A0, B1, acc[0][1]);  acc[1][1] = MFMA16(A1, B1, acc[1][1]);
        acc[2][1] = MFMA16(A2, B1, acc[2][1]);  acc[3][1] = MFMA16(A3, B1, acc[3][1]);
        acc[0][2] = MFMA16(A0, B2, acc[0][2]);  acc[1][2] = MFMA16(A1, B2, acc[1][2]);
        acc[2][2] = MFMA16(A2, B2, acc[2][2]);  acc[3][2] = MFMA16(A3, B2, acc[3][2]);
        acc[0][3] = MFMA16(A0, B3, acc[0][3]);  acc[1][3] = MFMA16(A1, B3, acc[1][3]);
        acc[2][3] = MFMA16(A2, B3, acc[2][3]);  acc[3][3] = MFMA16(A3, B3, acc[3][3]);
        __builtin_amdgcn_s_setprio(0);
    }

#pragma unroll
    for (int dd = 0; dd < 4; ++dd) {
#pragma unroll
        for (int n = 0; n < 4; ++n) {
            int o = obase + n * 16 + l15;
            float bias = b3d[o];
#pragma unroll
            for (int r4 = 0; r4 < 4; ++r4) {
                int u = u0 + lg * 4 + r4;
                if (u < 100)
                    m3b[((size_t)b * DU + (d0 + dd) * 100 + u) * 512 + o] =
                        f2bf(fmaxf(acc[dd][n][r4] + bias, 0.f));
            }
        }
    }
}

// ---------------------------------------------------------------------------
// m2b[b][du][k] = bf16(relu(b2d[k] + sum_o m3b*w2b))  -- MFMA GEMM
__global__ __launch_bounds__(256, 4)
void kM2m(const us* __restrict__ m3b, const us* __restrict__ w2b,
          const float* __restrict__ b2d, us* __restrict__ m2b) {
    int blk  = blockIdx.x;           // 4 * 157
    int tile = blk % 157;
    int b    = blk / 157;
    int du0  = tile * 64;
    int tid = threadIdx.x;
    int w   = tid >> 6;              // wave -> du sub-tile of 16
    int l   = tid & 63;
    int l15 = l & 15, lg = l >> 4;
    fx4 acc[8];
#pragma unroll
    for (int n = 0; n < 8; ++n) acc[n] = (fx4){0.f, 0.f, 0.f, 0.f};

    int dua = du0 + w * 16 + l15; if (dua > 9999) dua = 9999;   // ragged clamp
    const us* ap = m3b + ((size_t)b * DU + dua) * 512;
#pragma unroll 4
    for (int ks = 0; ks < 16; ++ks) {
        bfv8 a = *(const bfv8*)(ap + ks * 32 + lg * 8);
#pragma unroll
        for (int n = 0; n < 8; ++n) {
            bfv8 bq = *(const bfv8*)(w2b + (size_t)(n * 16 + l15) * 512 + ks * 32 + lg * 8);
            acc[n] = MFMA16(a, bq, acc[n]);
        }
    }
#pragma unroll
    for (int n = 0; n < 8; ++n) {
        int k = n * 16 + l15;
        float bias = b2d[k];
#pragma unroll
        for (int r = 0; r < 4; ++r) {
            int du = du0 + w * 16 + lg * 4 + r;
            if (du < DU)
                m2b[((size_t)b * DU + du) * 128 + k] = f2bf(fmaxf(acc[n][r] + bias, 0.f));
        }
    }
}

// ---------------------------------------------------------------------------
// 3x3 conv 128->128 (bf16 in), implicit GEMM, T3 2-phase W pipeline.
// HEAD=0: write bf16 fout.  HEAD=1: fuse 2-ch head + sigmoid, write hout.
template<int HEAD>
__global__ __launch_bounds__(256, 2)
void kConvM(const us* __restrict__ fin, const us* __restrict__ wfb,
            const float* __restrict__ bf, us* __restrict__ fout,
            const float* __restrict__ wf3, const float* __restrict__ bf3,
            float* __restrict__ hout) {
    __shared__ us slab[6 * 18 * 128];   // 27.6 KB, XOR-swizzled rows (256B pitch)
    __shared__ us wl2[2][8192];         // 2 x 16 KB: [k(128)][c-half(64)], 128B pitch
    int blk = blockIdx.x;            // b*175 + dt*7 + ut = 700
    int ut = blk % 7;
    int dt = (blk / 7) % 25;
    int b  = blk / 175;
    int u0 = ut * 16, d0 = dt * 4;
    int tid = threadIdx.x;
    int w   = tid >> 6;
    int l   = tid & 63;
    int l15 = l & 15, lg = l >> 4;
    fx4 acc[8];
#pragma unroll
    for (int n = 0; n < 8; ++n) acc[n] = (fx4){0.f, 0.f, 0.f, 0.f};

#define STAGE_W(BUF, P)                                                        \
    {   const int tap_ = (P) >> 1, ch_ = (P) & 1;                              \
        const us* wsrc = wfb + (size_t)tap_ * 16384 + ch_ * 64;                \
        _Pragma("unroll")                                                      \
        for (int rr = 0; rr < 4; ++rr) {                                       \
            int seg = rr * 4 + w;                                              \
            int off = seg * 1024 + l * 16;                                     \
            int k_ = off >> 7, cb_ = off & 127;                                \
            int cbs = cb_ ^ ((k_ & 7) << 4);                                   \
            gload16(wsrc + (size_t)k_ * 128 + (cbs >> 1),                      \
                    (char*)&wl2[BUF][0] + seg * 1024);                         \
        }                                                                      \
    }

    // stage input slab (bf16): rows (dd,uu) = fin[b][d0-1+dd][u0-1+uu][c]
    for (int i = tid; i < 1728; i += 256) {         // 16B chunks (8 c each)
        int cc = i & 15;
        int uu = (i >> 4) % 18;
        int dd = (i >> 4) / 18;
        int dr = d0 - 1 + dd, su = u0 - 1 + uu;
        uint4 v = {0u, 0u, 0u, 0u};
        if (dr >= 0 && dr < 100 && su >= 0 && su < 100)
            v = *(const uint4*)(fin + ((size_t)b * DU + dr * 100 + su) * 128 + cc * 8);
        int byte = (dd * 18 + uu) * 256 + ((cc * 16) ^ ((uu & 7) << 4));
        *(uint4*)((char*)slab + byte) = v;
    }
    STAGE_W(0, 0)
    __syncthreads();                                 // slab + W(0) ready

#pragma unroll
    for (int p = 0; p < 18; ++p) {
        if (p + 1 < 18) STAGE_W((p + 1) & 1, p + 1)  // prefetch next W tile
        const int tap = p >> 1, ch = p & 1;
        const int dy = tap / 3, dx = tap % 3;
        int uu = l15 + dx;
        int ddr = w + dy;
        int arow = (ddr * 18 + uu) * 256;
        int aswz = (uu & 7) << 4;
        const char* wbuf = (const char*)&wl2[p & 1][0];
#pragma unroll
        for (int cs = 0; cs < 2; ++cs) {
            int cbyte = ch * 128 + cs * 64 + lg * 16;    // slab byte within row
            bfv8 a = *(const bfv8*)((const char*)slab + arow + (cbyte ^ aswz));
            int wcb = cs * 64 + lg * 16;                 // W byte within row
#pragma unroll
            for (int n = 0; n < 8; ++n) {
                int k = n * 16 + l15;
                bfv8 bq = *(const bfv8*)(wbuf + k * 128 + (wcb ^ ((k & 7) << 4)));
                acc[n] = MFMA16(a, bq, acc[n]);
            }
        }
        __syncthreads();    // drains gload vmcnt: next buffer ready; reads done
    }
#undef STAGE_W

    int d = d0 + w;
    if (HEAD == 0) {
#pragma unroll
        for (int n = 0; n < 8; ++n) {
            int k = n * 16 + l15;
            float bias = bf[k];
#pragma unroll
            for (int r = 0; r < 4; ++r) {
                int u = u0 + lg * 4 + r;
                if (u < 100)
                    fout[((size_t)b * DU + d * 100 + u) * 128 + k] =
                        f2bf(fmaxf(acc[n][r] + bias, 0.f));
            }
        }
    } else {
#pragma unroll
        for (int r = 0; r < 4; ++r) {
            float p0 = 0.f, p1 = 0.f;
#pragma unroll
            for (int n = 0; n < 8; ++n) {
                int k = n * 16 + l15;
                float f = fmaxf(acc[n][r] + bf[k], 0.f);
                p0 = fmaf(f, wf3[k], p0);
                p1 = fmaf(f, wf3[128 + k], p1);
            }
            p0 += __shfl_xor(p0, 1); p0 += __shfl_xor(p0, 2);
            p0 += __shfl_xor(p0, 4); p0 += __shfl_xor(p0, 8);
            p1 += __shfl_xor(p1, 1); p1 += __shfl_xor(p1, 2);
            p1 += __shfl_xor(p1, 4); p1 += __shfl_xor(p1, 8);
            int u = u0 + lg * 4 + r;
            if (l15 == 0 && u < 100) {
                int du = d * 100 + u;
                hout[((size_t)b * 2 + 0) * DU + du] = 1.f / (1.f + expf(-(p0 + bf3[0])));
                hout[((size_t)b * 2 + 1) * DU + du] = 1.f / (1.f + expf(-(p1 + bf3[1])));
            }
        }
    }
}

// ---------------------------------------------------------------------------
extern "C" void kernel_launch(void* const* d_in, const int* in_sizes, int n_in,
                              void* d_out, int out_size, void* d_ws, size_t ws_size,
                              hipStream_t stream) {
    const float* x    = (const float*)d_in[0];
    const float* wrd  = (const float*)d_in[1];
    const float* brd  = (const float*)d_in[2];
    const float* w3d  = (const float*)d_in[3];
    const float* b3d  = (const float*)d_in[4];
    const float* w2d  = (const float*)d_in[5];
    const float* b2d  = (const float*)d_in[6];
    const float* wf1  = (const float*)d_in[7];
    const float* bf1  = (const float*)d_in[8];
    const float* wf2  = (const float*)d_in[9];
    const float* bf2  = (const float*)d_in[10];
    const float* wf3  = (const float*)d_in[11];
    const float* bf3  = (const float*)d_in[12];
    const float* mask = (const float*)d_in[13];

    float* ws = (float*)d_ws;
    // layout (float-unit offsets)
    us* hT    = (us*)(ws + 0);            //    65,536 us -> [0, 32768)
    us* w3B   = (us*)(ws + 32768);        // 2,097,152 us -> [32768, 1081344)
    us* w2b   = (us*)(ws + 1081344);      //    65,536 us -> [.., 1114112)
    us* wfb1  = (us*)(ws + 1114112);      //   147,456 us -> [.., 1187840)
    us* wfb2  = (us*)(ws + 1187840);      //   147,456 us -> [.., 1261568)
    us* QT    = (us*)(ws + 1261568);      // 8,388,608 us -> [.., 5455872)
    us* maskW = (us*)(ws + 5455872);      // 11,468,800 us -> [.., 11190272)
    us* m2b   = (us*)(ws + 5455872);      // alias maskW (dead after kM3m)
    us* f1b   = (us*)(ws + 8015872);      // alias maskW tail
    us* m3b   = (us*)(ws + 11190272);     // 20,480,000 us -> [.., 21430272)

    kFront<<<15456, 256, 0, stream>>>(w3d, w3B, w2d, w2b, wf1, wfb1, wf2, wfb2,
                                      x, wrd, brd, hT, mask, maskW);
    kQm<<<256, 256, 0, stream>>>(w3B, hT, QT);
    kM3m<<<2800, 128, 0, stream>>>(maskW, QT, b3d, m3b);
    kM2m<<<B * 157, 256, 0, stream>>>(m3b, w2b, b2d, m2b);
    kConvM<0><<<B * 25 * 7, 256, 0, stream>>>(m2b, wfb1, bf1, f1b,
                                              nullptr, nullptr, nullptr);
    kConvM<1><<<B * 25 * 7, 256, 0, stream>>>(f1b, wfb2, bf2, nullptr,
                                              wf3, bf3, (float*)d_out);
}